// Round 1
// 846.397 us; speedup vs baseline: 1.0480x; 1.0480x over previous
//
#include <hip/hip_runtime.h>

#define N_NODES 50000
#define N_EDGES 10000
#define N_INC   800000
// IN_F=64, HID=64, concat width 128.
// Input dtype (f32 vs raw-bf16) detected on device (k_detect) — f32 confirmed in R8.
// X1 AND m intermediates stored bf16. R17: k_count drops float-D atomic (D via CSR
// post-pass k_dinv), nlist stored u16, sentinel removed.
// R18: k_fill -> k_fill8 (XCD-range-partitioned scatter: key range = blockIdx%8 so
// all writers of a CSR dest line share one XCD L2; dest slice ~200KB/XCD stays
// resident -> store merging in L2, WRITE_SIZE ~102MB -> ~payload). elist now u16
// (node ids < 65536). Two gate edge-gather launches merged into one (64 thr/edge).

__device__ float bf2f(unsigned short u){
    return __uint_as_float(((unsigned)u) << 16);
}
__device__ unsigned short f2bf(float f){
    unsigned u = __float_as_uint(f);
    unsigned r = u + 0x7FFFu + ((u >> 16) & 1u);
    return (unsigned short)(r >> 16);
}
__device__ float ldv(const void* p, int i, int bf){
    if (bf) return bf2f(((const unsigned short*)p)[i]);
    return ((const float*)p)[i];
}

#define ACC8(A) float A##0=0.f,A##1=0.f,A##2=0.f,A##3=0.f,A##4=0.f,A##5=0.f,A##6=0.f,A##7=0.f
#define FMA8(A,a,b) A##0+=(a)*u0+(b)*v0; A##1+=(a)*u1+(b)*v1; A##2+=(a)*u2+(b)*v2; \
                    A##3+=(a)*u3+(b)*v3; A##4+=(a)*u4+(b)*v4; A##5+=(a)*u5+(b)*v5; \
                    A##6+=(a)*u6+(b)*v6; A##7+=(a)*u7+(b)*v7
#define STORE8(A,o) (o)[0]=f2bf(A##0);(o)[1]=f2bf(A##1);(o)[2]=f2bf(A##2);(o)[3]=f2bf(A##3); \
                    (o)[4]=f2bf(A##4);(o)[5]=f2bf(A##5);(o)[6]=f2bf(A##6);(o)[7]=f2bf(A##7)

__global__ void k_detect(const unsigned short* hw, int* flag){
    if (blockIdx.x == 0 && threadIdx.x == 0){
        int ok = 1;
        for (int j = 0; j < 64; ++j){
            float v = bf2f(hw[j]);
            if (!(v > 0.05f && v < 1.2f)) ok = 0;
        }
        *flag = ok;
    }
}

__global__ void k_zero(float* p, int n){
    int i = blockIdx.x*256 + threadIdx.x;
    if (i < n) p[i] = 0.f;
}

// counts: node degree Dc, edge cardinality Bc (int atomics only)
__global__ void k_count(const int* nidx, const int* eidx, int* Dc, int* Bc){
    int i = blockIdx.x*256 + threadIdx.x;
    if (i < N_INC){
        atomicAdd(&Dc[nidx[i]], 1);
        atomicAdd(&Bc[eidx[i]], 1);
    }
}

// Binv from Bc
__global__ void k_binv(const int* Bc, float* Binv){
    int i = blockIdx.x*256 + threadIdx.x;
    if (i < N_EDGES) Binv[i] = Bc[i] > 0 ? 1.f/(float)Bc[i] : 0.f;
}

// Dinv via CSR: D[n] = sum hw[e] over incident edges (nlist u16), then invert.
__global__ void k_dinv(const int* indptr_n, const int* Dc,
                       const unsigned short* nlist, const void* hw,
                       float* Dinv, const int* flag){
    int bf = *flag;
    int n = blockIdx.x*256 + threadIdx.x;
    if (n >= N_NODES) return;
    int beg = indptr_n[n], cnt = Dc[n];
    float s = 0.f;
    for (int j = 0; j < cnt; ++j){
        int e = nlist[beg + j];
        s += ldv(hw, e, bf);
    }
    Dinv[n] = s > 0.f ? 1.f/s : 0.f;
}

// ---- chunked exclusive scan, no LDS ----
__global__ void k_chunksum(const int* cnt, int* csum, int n, int nchunks){
    int ch = blockIdx.x*256 + threadIdx.x;
    if (ch >= nchunks) return;
    int beg = ch*128, end = beg + 128;
    if (end > n) end = n;
    int s = 0;
    for (int i = beg; i < end; ++i) s += cnt[i];
    csum[ch] = s;
}
__global__ void k_chunkscan(const int* csum, int* cbase, int nchunks){
    if (blockIdx.x == 0 && threadIdx.x == 0){
        int run = 0;
        for (int ch = 0; ch < nchunks; ++ch){
            cbase[ch] = run;
            run += csum[ch];
        }
    }
}
__global__ void k_chunkfill(const int* cnt, const int* cbase, int* indptr,
                            int* cursor, int n, int nchunks){
    int ch = blockIdx.x*256 + threadIdx.x;
    if (ch >= nchunks) return;
    int beg = ch*128, end = beg + 128;
    if (end > n) end = n;
    int run = cbase[ch];
    for (int i = beg; i < end; ++i){
        indptr[i] = run;
        cursor[i] = run;
        run += cnt[i];
    }
}

// XCD-range-partitioned CSR fill. blockIdx%8 selects a key range; under the
// round-robin block->XCD dispatch, all writers of a given CSR destination line
// live on one XCD, so its L2 merges the scattered u16 stores before writeback.
// Dest slice per range: ~100K nlist entries (200KB) + ~100K elist entries (200KB).
__global__ void k_fill8(const int* nidx, const int* eidx,
                        int* cursor_n, unsigned short* nlist,
                        int* cursor_e, unsigned short* elist){
    int seg   = blockIdx.x & 7;
    int chunk = blockIdx.x >> 3;
    int i = chunk*256 + threadIdx.x;
    if (i >= N_INC) return;
    int n = nidx[i];
    int e = eidx[i];
    if (n / 6250 == seg){                 // 50000/8 = 6250
        int pn = atomicAdd(&cursor_n[n], 1);
        nlist[pn] = (unsigned short)e;
    }
    if (e / 1250 == seg){                 // 10000/8 = 1250
        int pe = atomicAdd(&cursor_e[e], 1);
        elist[pe] = (unsigned short)n;
    }
}

// gate GEMM v3: 4 nodes x 8 cols per thread (block = 64 nodes x 128 cols).
__global__ void k_gemm_gate(const void* x, const void* st, const void* W,
                            unsigned short* X1b, const int* flag){
    int bf = *flag;
    int tid = threadIdx.x;
    int c0 = (tid & 15) * 8;
    int n0 = blockIdx.x*64 + (tid >> 4)*4;
    int g0 = n0 < N_NODES, g1 = n0+1 < N_NODES, g2 = n0+2 < N_NODES, g3 = n0+3 < N_NODES;
    ACC8(A); ACC8(B); ACC8(C); ACC8(D);
    int i0 = n0*64;
    if (bf){
        const unsigned short* Wh = (const unsigned short*)W;
        const unsigned short* xh = (const unsigned short*)x;
        const unsigned short* sh = (const unsigned short*)st;
        for (int k = 0; k < 64; ++k){
            const unsigned short* w0 = Wh + k*128 + c0;
            const unsigned short* w1 = w0 + 64*128;
            float u0=bf2f(w0[0]),u1=bf2f(w0[1]),u2=bf2f(w0[2]),u3=bf2f(w0[3]),
                  u4=bf2f(w0[4]),u5=bf2f(w0[5]),u6=bf2f(w0[6]),u7=bf2f(w0[7]);
            float v0=bf2f(w1[0]),v1=bf2f(w1[1]),v2=bf2f(w1[2]),v3=bf2f(w1[3]),
                  v4=bf2f(w1[4]),v5=bf2f(w1[5]),v6=bf2f(w1[6]),v7=bf2f(w1[7]);
            float a, b;
            a = g0?bf2f(xh[i0+k]):0.f;     b = g0?bf2f(sh[i0+k]):0.f;     FMA8(A,a,b);
            a = g1?bf2f(xh[i0+64+k]):0.f;  b = g1?bf2f(sh[i0+64+k]):0.f;  FMA8(B,a,b);
            a = g2?bf2f(xh[i0+128+k]):0.f; b = g2?bf2f(sh[i0+128+k]):0.f; FMA8(C,a,b);
            a = g3?bf2f(xh[i0+192+k]):0.f; b = g3?bf2f(sh[i0+192+k]):0.f; FMA8(D,a,b);
        }
    } else {
        const float* Wf = (const float*)W;
        const float* xf = (const float*)x;
        const float* sf = (const float*)st;
        for (int k = 0; k < 64; ++k){
            const float* w0 = Wf + k*128 + c0;
            const float* w1 = w0 + 64*128;
            float u0=w0[0],u1=w0[1],u2=w0[2],u3=w0[3],u4=w0[4],u5=w0[5],u6=w0[6],u7=w0[7];
            float v0=w1[0],v1=w1[1],v2=w1[2],v3=w1[3],v4=w1[4],v5=w1[5],v6=w1[6],v7=w1[7];
            float a, b;
            a = g0?xf[i0+k]:0.f;     b = g0?sf[i0+k]:0.f;     FMA8(A,a,b);
            a = g1?xf[i0+64+k]:0.f;  b = g1?sf[i0+64+k]:0.f;  FMA8(B,a,b);
            a = g2?xf[i0+128+k]:0.f; b = g2?sf[i0+128+k]:0.f; FMA8(C,a,b);
            a = g3?xf[i0+192+k]:0.f; b = g3?sf[i0+192+k]:0.f; FMA8(D,a,b);
        }
    }
    if (g0){ unsigned short* o = X1b + n0*128 + c0;       STORE8(A,o); }
    if (g1){ unsigned short* o = X1b + (n0+1)*128 + c0;   STORE8(B,o); }
    if (g2){ unsigned short* o = X1b + (n0+2)*128 + c0;   STORE8(C,o); }
    if (g3){ unsigned short* o = X1b + (n0+3)*128 + c0;   STORE8(D,o); }
}

// cand GEMM v3: same tiling; cols 0-63 from Wc, 64-127 from Wr; second operand rs (f32).
__global__ void k_gemm_cand(const void* x, const float* rs, const void* Wc,
                            const void* Wr, unsigned short* X1b, const int* flag){
    int bf = *flag;
    int tid = threadIdx.x;
    int cq = tid & 15;
    int c0 = cq * 8;
    int cc = c0 & 63;
    int n0 = blockIdx.x*64 + (tid >> 4)*4;
    int g0 = n0 < N_NODES, g1 = n0+1 < N_NODES, g2 = n0+2 < N_NODES, g3 = n0+3 < N_NODES;
    const void* Wsel = (cq < 8) ? Wc : Wr;
    ACC8(A); ACC8(B); ACC8(C); ACC8(D);
    int i0 = n0*64;
    if (bf){
        const unsigned short* Wh = (const unsigned short*)Wsel;
        const unsigned short* xh = (const unsigned short*)x;
        for (int k = 0; k < 64; ++k){
            const unsigned short* w0 = Wh + k*64 + cc;
            const unsigned short* w1 = w0 + 64*64;
            float u0=bf2f(w0[0]),u1=bf2f(w0[1]),u2=bf2f(w0[2]),u3=bf2f(w0[3]),
                  u4=bf2f(w0[4]),u5=bf2f(w0[5]),u6=bf2f(w0[6]),u7=bf2f(w0[7]);
            float v0=bf2f(w1[0]),v1=bf2f(w1[1]),v2=bf2f(w1[2]),v3=bf2f(w1[3]),
                  v4=bf2f(w1[4]),v5=bf2f(w1[5]),v6=bf2f(w1[6]),v7=bf2f(w1[7]);
            float a, b;
            a = g0?bf2f(xh[i0+k]):0.f;     b = g0?rs[i0+k]:0.f;     FMA8(A,a,b);
            a = g1?bf2f(xh[i0+64+k]):0.f;  b = g1?rs[i0+64+k]:0.f;  FMA8(B,a,b);
            a = g2?bf2f(xh[i0+128+k]):0.f; b = g2?rs[i0+128+k]:0.f; FMA8(C,a,b);
            a = g3?bf2f(xh[i0+192+k]):0.f; b = g3?rs[i0+192+k]:0.f; FMA8(D,a,b);
        }
    } else {
        const float* Wf = (const float*)Wsel;
        const float* xf = (const float*)x;
        for (int k = 0; k < 64; ++k){
            const float* w0 = Wf + k*64 + cc;
            const float* w1 = w0 + 64*64;
            float u0=w0[0],u1=w0[1],u2=w0[2],u3=w0[3],u4=w0[4],u5=w0[5],u6=w0[6],u7=w0[7];
            float v0=w1[0],v1=w1[1],v2=w1[2],v3=w1[3],v4=w1[4],v5=w1[5],v6=w1[6],v7=w1[7];
            float a, b;
            a = g0?xf[i0+k]:0.f;     b = g0?rs[i0+k]:0.f;     FMA8(A,a,b);
            a = g1?xf[i0+64+k]:0.f;  b = g1?rs[i0+64+k]:0.f;  FMA8(B,a,b);
            a = g2?xf[i0+128+k]:0.f; b = g2?rs[i0+128+k]:0.f; FMA8(C,a,b);
            a = g3?xf[i0+192+k]:0.f; b = g3?rs[i0+192+k]:0.f; FMA8(D,a,b);
        }
    }
    if (g0){ unsigned short* o = X1b + n0*128 + c0;       STORE8(A,o); }
    if (g1){ unsigned short* o = X1b + (n0+1)*128 + c0;   STORE8(B,o); }
    if (g2){ unsigned short* o = X1b + (n0+2)*128 + c0;   STORE8(C,o); }
    if (g3){ unsigned short* o = X1b + (n0+3)*128 + c0;   STORE8(D,o); }
}

// gate edge gather (merged, 64 threads/edge -> all 128 cols in one traversal,
// no intra-wave cnt divergence). bf16 X1 in, bf16 m out (packed u32 pair store).
__global__ void k_gather_e_gate(const int* indptr_e, const int* Bc,
                                const unsigned short* elist,
                                const unsigned short* X1b, const void* hw,
                                const float* Binv, unsigned* mb, const int* flag){
    int bf = *flag;
    int t = blockIdx.x*256 + threadIdx.x;
    if (t >= N_EDGES*64) return;
    int e = t >> 6, p = t & 63;          // pair index 0..63 (128 bf16 cols)
    int beg = indptr_e[e], cnt = Bc[e];
    float acc0 = 0.f, acc1 = 0.f;
    for (int j = 0; j < cnt; ++j){
        int n = elist[beg + j];
        unsigned v = *(const unsigned*)(X1b + n*128 + p*2);
        acc0 += bf2f((unsigned short)(v & 0xFFFFu));
        acc1 += bf2f((unsigned short)(v >> 16));
    }
    float wsc = ldv(hw, e, bf) * Binv[e];
    unsigned lo = f2bf(acc0 * wsc);
    unsigned hi = f2bf(acc1 * wsc);
    mb[e*64 + p] = lo | (hi << 16);
}

// cand edge gather: 32 threads/edge, cols 0-63 of X1 (CP=32). elist u16.
__global__ void k_gather_e2(const int* indptr_e, const int* Bc,
                            const unsigned short* elist,
                            const unsigned short* X1b, const void* hw,
                            const float* Binv, unsigned* mb, int pairBase, int CP,
                            const int* flag){
    int bf = *flag;
    int t = blockIdx.x*256 + threadIdx.x;
    if (t >= N_EDGES*32) return;
    int e = t >> 5, p = t & 31;
    int cp = pairBase + p;
    int beg = indptr_e[e], cnt = Bc[e];
    float acc0 = 0.f, acc1 = 0.f;
    for (int j = 0; j < cnt; ++j){
        int n = elist[beg + j];
        unsigned v = *(const unsigned*)(X1b + n*128 + cp*2);
        acc0 += bf2f((unsigned short)(v & 0xFFFFu));
        acc1 += bf2f((unsigned short)(v >> 16));
    }
    float wsc = ldv(hw, e, bf) * Binv[e];
    unsigned lo = f2bf(acc0 * wsc);
    unsigned hi = f2bf(acc1 * wsc);
    mb[e*CP + cp] = lo | (hi << 16);     // CP = C/2 pairs per edge
}

// fused node gather + gate prep: thread per (node, 4-col group), m bf16, nlist u16.
__global__ void k_gather_prep_gate(const int* indptr_n, const int* Dc,
                                   const unsigned short* nlist, const unsigned* mb,
                                   const void* x, const void* st,
                                   const float* Dinv, const void* gb,
                                   float* P, const int* flag){
    int bf = *flag;
    int t = blockIdx.x*256 + threadIdx.x;
    if (t >= N_NODES*32) return;
    int n = t >> 5, g = t & 31;
    int c = g*4;
    int beg = indptr_n[n], cnt = Dc[n];
    float a0 = 0.f, a1 = 0.f, a2 = 0.f, a3 = 0.f;
    for (int j = 0; j < cnt; ++j){
        int e = nlist[beg + j];
        const unsigned* q = mb + e*64 + g*2;
        unsigned va = q[0], vb = q[1];
        a0 += bf2f((unsigned short)(va & 0xFFFFu));
        a1 += bf2f((unsigned short)(va >> 16));
        a2 += bf2f((unsigned short)(vb & 0xFFFFu));
        a3 += bf2f((unsigned short)(vb >> 16));
    }
    float di = Dinv[n];
    float b0, b1, b2, b3;
    if (c < 64){
        b0 = ldv(x, n*64 + c, bf);     b1 = ldv(x, n*64 + c + 1, bf);
        b2 = ldv(x, n*64 + c + 2, bf); b3 = ldv(x, n*64 + c + 3, bf);
    } else {
        int cc = c - 64;
        b0 = ldv(st, n*64 + cc, bf);     b1 = ldv(st, n*64 + cc + 1, bf);
        b2 = ldv(st, n*64 + cc + 2, bf); b3 = ldv(st, n*64 + cc + 3, bf);
    }
    float v0 = b0 + di*a0 + ldv(gb, c, bf);
    float v1 = b1 + di*a1 + ldv(gb, c + 1, bf);
    float v2 = b2 + di*a2 + ldv(gb, c + 2, bf);
    float v3 = b3 + di*a3 + ldv(gb, c + 3, bf);
    if (v0 < 0.f) v0 = 0.f;
    if (v1 < 0.f) v1 = 0.f;
    if (v2 < 0.f) v2 = 0.f;
    if (v3 < 0.f) v3 = 0.f;
    float* o = P + n*128 + c;
    o[0] = v0; o[1] = v1; o[2] = v2; o[3] = v3;
}

// fused node gather + cand prep: thread per (node, 4-col group), m bf16 (CP=32), nlist u16.
__global__ void k_gather_prep_cand(const int* indptr_n, const int* Dc,
                                   const unsigned short* nlist, const unsigned* mb,
                                   const unsigned short* X1b, const float* Dinv,
                                   const void* cbv, const void* crb,
                                   float* P2, const int* flag){
    int bf = *flag;
    int t = blockIdx.x*256 + threadIdx.x;
    if (t >= N_NODES*16) return;
    int n = t >> 4, g = t & 15;
    int c = g*4;
    int beg = indptr_n[n], cnt = Dc[n];
    float a0 = 0.f, a1 = 0.f, a2 = 0.f, a3 = 0.f;
    for (int j = 0; j < cnt; ++j){
        int e = nlist[beg + j];
        const unsigned* q = mb + e*32 + g*2;
        unsigned va = q[0], vb = q[1];
        a0 += bf2f((unsigned short)(va & 0xFFFFu));
        a1 += bf2f((unsigned short)(va >> 16));
        a2 += bf2f((unsigned short)(vb & 0xFFFFu));
        a3 += bf2f((unsigned short)(vb >> 16));
    }
    float di = Dinv[n];
    float v0 = bf2f(X1b[n*128 + 64 + c])     + ldv(crb, c, bf)     + di*a0 + ldv(cbv, c, bf);
    float v1 = bf2f(X1b[n*128 + 64 + c + 1]) + ldv(crb, c + 1, bf) + di*a1 + ldv(cbv, c + 1, bf);
    float v2 = bf2f(X1b[n*128 + 64 + c + 2]) + ldv(crb, c + 2, bf) + di*a2 + ldv(cbv, c + 2, bf);
    float v3 = bf2f(X1b[n*128 + 64 + c + 3]) + ldv(crb, c + 3, bf) + di*a3 + ldv(cbv, c + 3, bf);
    if (v0 < 0.f) v0 = 0.f;
    if (v1 < 0.f) v1 = 0.f;
    if (v2 < 0.f) v2 = 0.f;
    if (v3 < 0.f) v3 = 0.f;
    float* o = P2 + n*64 + c;
    o[0] = v0; o[1] = v1; o[2] = v2; o[3] = v3;
}

// row stats: thread per node, 64-thread blocks (block footprint fits L1).
__global__ void k_stat(const float* P, float* pstat, int nrows, int C){
    int n = blockIdx.x*64 + threadIdx.x;
    if (n >= nrows) return;
    float s = 0.f, sq = 0.f;
    for (int c = 0; c < C; ++c){
        float v = P[n*C + c];
        s += v; sq += v*v;
    }
    pstat[n*2]     = s;
    pstat[n*2 + 1] = sq;
}

// gate fin: thread per (node, col<64).
__global__ void k_gate_fin2(const void* st, const float* P, const float* pstat,
                            const void* lng, const void* lnb,
                            float* zbuf, float* rs, const int* flag){
    int bf = *flag;
    int t = blockIdx.x*256 + threadIdx.x;
    if (t >= N_NODES*64) return;
    int n = t >> 6, c = t & 63;
    float s  = pstat[2*n];
    float sq = pstat[2*n + 1];
    float mu = s * (1.f/128.f);
    float var = sq * (1.f/128.f) - mu*mu;
    if (var < 0.f) var = 0.f;
    float inv = 1.f / sqrtf(var + 1e-5f);
    float v0 = P[n*128 + c];
    float v1 = P[n*128 + 64 + c];
    float u0 = (v0 - mu)*inv*ldv(lng, c, bf)      + ldv(lnb, c, bf);
    float u1 = (v1 - mu)*inv*ldv(lng, 64 + c, bf) + ldv(lnb, 64 + c, bf);
    float z = 1.f/(1.f + expf(-u0));
    float r = 1.f/(1.f + expf(-u1));
    float s1 = ldv(st, t, bf);
    zbuf[t] = z;
    rs[t]   = r * s1;
}

// cand fin: thread per (node, col). LN + tanh + GRU blend -> out.
__global__ void k_cand_fin2(const void* st, const float* P2, const float* pstat,
                            const void* lng, const void* lnb, const float* zbuf,
                            void* out, const int* flag){
    int bf = *flag;
    int t = blockIdx.x*256 + threadIdx.x;
    if (t >= N_NODES*64) return;
    int n = t >> 6, c = t & 63;
    float s  = pstat[2*n];
    float sq = pstat[2*n + 1];
    float mu = s * (1.f/64.f);
    float var = sq * (1.f/64.f) - mu*mu;
    if (var < 0.f) var = 0.f;
    float inv = 1.f / sqrtf(var + 1e-5f);
    float v = P2[t];
    float u = (v - mu)*inv*ldv(lng, c, bf) + ldv(lnb, c, bf);
    float hc = tanhf(u);
    float z = zbuf[t];
    float sv = ldv(st, t, bf);
    float res = (1.f - z)*sv + z*hc;
    if (bf) ((unsigned short*)out)[t] = f2bf(res);
    else    ((float*)out)[t] = res;
}

extern "C" void kernel_launch(void* const* d_in, const int* in_sizes, int n_in,
                              void* d_out, int out_size, void* d_ws, size_t ws_size,
                              hipStream_t stream){
    const void* x      = d_in[0];
    const void* state  = d_in[1];
    const int*  hidx   = (const int*)d_in[2];
    const void* hw     = d_in[3];
    const void* gate_W = d_in[4];
    const void* gate_b = d_in[5];
    const void* glng   = d_in[6];
    const void* glnb   = d_in[7];
    const void* cand_W = d_in[8];
    const void* cand_b = d_in[9];
    const void* clng   = d_in[10];
    const void* clnb   = d_in[11];
    const void* crW    = d_in[12];
    const void* crb    = d_in[13];
    (void)in_sizes; (void)n_in; (void)ws_size; (void)out_size;

    const int* nidx = hidx;
    const int* eidx = hidx + N_INC;

    const int NCH_N = (N_NODES + 127)/128;   // 391
    const int NCH_E = (N_EDGES + 127)/128;   // 79

    // ---- workspace (byte offsets, 256B-aligned, total ~73.5 MB) ----
    char* w = (char*)d_ws;
    int*   flag     = (int*)  (w);
    float* Dinv     = (float*)(w + 256);        // 50048 f (computed by k_dinv)
    int*   Bc       = (int*)  (w + 200448);     // 10048 i  (Bc,Dc contiguous: zeroed)
    int*   Dc       = (int*)  (w + 240640);     // 50048 i
    float* Binv     = (float*)(w + 440832);     // 10048 f
    int*   indptr_n = (int*)  (w + 481024);     // 50048 i
    int*   cursor_n = (int*)  (w + 681216);     // 50048 i
    int*   indptr_e = (int*)  (w + 881408);     // 10048 i
    int*   cursor_e = (int*)  (w + 921600);     // 10048 i
    int*   csum_n   = (int*)  (w + 961792);     // 512 i
    int*   cbase_n  = (int*)  (w + 963840);     // 512 i
    int*   csum_e   = (int*)  (w + 965888);     // 256 i
    int*   cbase_e  = (int*)  (w + 966912);     // 256 i
    unsigned short* nlist = (unsigned short*)(w + 967936);  // 800000 u16
    unsigned short* elist = (unsigned short*)(w + 2567936); // 800000 u16 (node ids < 65536)
    unsigned* mb    = (unsigned*)(w + 5767936); // 10000*64 u32 (=128 bf16 cols)
    unsigned short* X1b = (unsigned short*)(w + 8327936);   // 50000*128 u16
    float* P        = (float*)(w + 21127936);   // 50000*128 f (gate P; cand P2 aliases)
    float* P2       = P;
    float* zbuf     = (float*)(w + 46727936);   // 50000*64 f
    float* rs       = (float*)(w + 59527936);   // 50000*64 f
    float* pstat_g  = (float*)(w + 72327936);   // 100000 f
    float* pstat_c  = (float*)(w + 73127936);   // 100000 f -> ends 73527936

    // dtype detect
    k_detect<<<1, 64, 0, stream>>>((const unsigned short*)hw, flag);

    // zero Bc,Dc (contiguous 60096 words)
    k_zero<<<(60096 + 255)/256, 256, 0, stream>>>((float*)(w + 200448), 60096);

    // degrees + CSR build
    k_count<<<(N_INC + 255)/256, 256, 0, stream>>>(nidx, eidx, Dc, Bc);
    k_binv<<<(N_EDGES + 255)/256, 256, 0, stream>>>(Bc, Binv);
    k_chunksum<<<(NCH_N + 255)/256, 256, 0, stream>>>(Dc, csum_n, N_NODES, NCH_N);
    k_chunkscan<<<1, 64, 0, stream>>>(csum_n, cbase_n, NCH_N);
    k_chunkfill<<<(NCH_N + 255)/256, 256, 0, stream>>>(Dc, cbase_n, indptr_n, cursor_n,
                                                       N_NODES, NCH_N);
    k_chunksum<<<(NCH_E + 255)/256, 256, 0, stream>>>(Bc, csum_e, N_EDGES, NCH_E);
    k_chunkscan<<<1, 64, 0, stream>>>(csum_e, cbase_e, NCH_E);
    k_chunkfill<<<(NCH_E + 255)/256, 256, 0, stream>>>(Bc, cbase_e, indptr_e, cursor_e,
                                                       N_EDGES, NCH_E);
    k_fill8<<<8*((N_INC + 255)/256), 256, 0, stream>>>(nidx, eidx, cursor_n, nlist,
                                                       cursor_e, elist);
    k_dinv<<<(N_NODES + 255)/256, 256, 0, stream>>>(indptr_n, Dc, nlist, hw, Dinv, flag);

    // ---- gate path ----
    k_gemm_gate<<<(N_NODES + 63)/64, 256, 0, stream>>>(x, state, gate_W, X1b, flag);
    k_gather_e_gate<<<(N_EDGES*64 + 255)/256, 256, 0, stream>>>(indptr_e, Bc, elist,
                                                                X1b, hw, Binv, mb, flag);
    k_gather_prep_gate<<<(N_NODES*32 + 255)/256, 256, 0, stream>>>(indptr_n, Dc, nlist,
                                                                   mb, x, state, Dinv,
                                                                   gate_b, P, flag);
    k_stat<<<(N_NODES + 63)/64, 64, 0, stream>>>(P, pstat_g, N_NODES, 128);
    k_gate_fin2<<<(N_NODES*64 + 255)/256, 256, 0, stream>>>(state, P, pstat_g,
                                                            glng, glnb, zbuf, rs, flag);

    // ---- candidate path ----
    k_gemm_cand<<<(N_NODES + 63)/64, 256, 0, stream>>>(x, rs, cand_W, crW, X1b, flag);
    k_gather_e2<<<(N_EDGES*32 + 255)/256, 256, 0, stream>>>(indptr_e, Bc, elist, X1b,
                                                            hw, Binv, mb, 0, 32, flag);
    k_gather_prep_cand<<<(N_NODES*16 + 255)/256, 256, 0, stream>>>(indptr_n, Dc, nlist,
                                                                   mb, X1b, Dinv, cand_b,
                                                                   crb, P2, flag);
    k_stat<<<(N_NODES + 63)/64, 64, 0, stream>>>(P2, pstat_c, N_NODES, 64);
    k_cand_fin2<<<(N_NODES*64 + 255)/256, 256, 0, stream>>>(state, P2, pstat_c,
                                                            clng, clnb, zbuf,
                                                            d_out, flag);
}

// Round 2
// 718.217 us; speedup vs baseline: 1.2350x; 1.1785x over previous
//
#include <hip/hip_runtime.h>

#define N_NODES 50000
#define N_EDGES 10000
#define N_INC   800000
// IN_F=64, HID=64, concat width 128.
// Input dtype (f32 vs raw-bf16) detected on device (k_detect) — f32 confirmed in R8.
// X1 AND m intermediates stored bf16. R17: k_count drops float-D atomic, nlist u16.
// R18: k_fill8 XCD-range-partitioned scatter (WRITE_SIZE 102MB -> payload); elist u16;
// gate edge-gather merged to 64 thr/edge.
// R19: gather loops were 1-outstanding-load latency chains (VGPR=8, VALUBusy 10%,
// 775 GB/s = in-flight*latency limit). Unroll-by-8 (edge gathers) / by-4 (prep
// gathers, 2 loads/iter) with index prefetch -> 8 rows in flight per wave.
// Accumulation order preserved exactly (bitwise-identical sums).

__device__ float bf2f(unsigned short u){
    return __uint_as_float(((unsigned)u) << 16);
}
__device__ unsigned short f2bf(float f){
    unsigned u = __float_as_uint(f);
    unsigned r = u + 0x7FFFu + ((u >> 16) & 1u);
    return (unsigned short)(r >> 16);
}
__device__ float ldv(const void* p, int i, int bf){
    if (bf) return bf2f(((const unsigned short*)p)[i]);
    return ((const float*)p)[i];
}

#define ACC8(A) float A##0=0.f,A##1=0.f,A##2=0.f,A##3=0.f,A##4=0.f,A##5=0.f,A##6=0.f,A##7=0.f
#define FMA8(A,a,b) A##0+=(a)*u0+(b)*v0; A##1+=(a)*u1+(b)*v1; A##2+=(a)*u2+(b)*v2; \
                    A##3+=(a)*u3+(b)*v3; A##4+=(a)*u4+(b)*v4; A##5+=(a)*u5+(b)*v5; \
                    A##6+=(a)*u6+(b)*v6; A##7+=(a)*u7+(b)*v7
#define STORE8(A,o) (o)[0]=f2bf(A##0);(o)[1]=f2bf(A##1);(o)[2]=f2bf(A##2);(o)[3]=f2bf(A##3); \
                    (o)[4]=f2bf(A##4);(o)[5]=f2bf(A##5);(o)[6]=f2bf(A##6);(o)[7]=f2bf(A##7)

__global__ void k_detect(const unsigned short* hw, int* flag){
    if (blockIdx.x == 0 && threadIdx.x == 0){
        int ok = 1;
        for (int j = 0; j < 64; ++j){
            float v = bf2f(hw[j]);
            if (!(v > 0.05f && v < 1.2f)) ok = 0;
        }
        *flag = ok;
    }
}

__global__ void k_zero(float* p, int n){
    int i = blockIdx.x*256 + threadIdx.x;
    if (i < n) p[i] = 0.f;
}

// counts: node degree Dc, edge cardinality Bc (int atomics only)
__global__ void k_count(const int* nidx, const int* eidx, int* Dc, int* Bc){
    int i = blockIdx.x*256 + threadIdx.x;
    if (i < N_INC){
        atomicAdd(&Dc[nidx[i]], 1);
        atomicAdd(&Bc[eidx[i]], 1);
    }
}

// Binv from Bc
__global__ void k_binv(const int* Bc, float* Binv){
    int i = blockIdx.x*256 + threadIdx.x;
    if (i < N_EDGES) Binv[i] = Bc[i] > 0 ? 1.f/(float)Bc[i] : 0.f;
}

// Dinv via CSR: D[n] = sum hw[e] over incident edges (nlist u16), then invert.
__global__ void k_dinv(const int* indptr_n, const int* Dc,
                       const unsigned short* nlist, const void* hw,
                       float* Dinv, const int* flag){
    int bf = *flag;
    int n = blockIdx.x*256 + threadIdx.x;
    if (n >= N_NODES) return;
    int beg = indptr_n[n], cnt = Dc[n];
    float s = 0.f;
    int j = 0;
    for (; j + 4 <= cnt; j += 4){
        int e0 = nlist[beg+j+0], e1 = nlist[beg+j+1],
            e2 = nlist[beg+j+2], e3 = nlist[beg+j+3];
        float h0 = ldv(hw, e0, bf), h1 = ldv(hw, e1, bf),
              h2 = ldv(hw, e2, bf), h3 = ldv(hw, e3, bf);
        s += h0; s += h1; s += h2; s += h3;
    }
    for (; j < cnt; ++j){
        int e = nlist[beg + j];
        s += ldv(hw, e, bf);
    }
    Dinv[n] = s > 0.f ? 1.f/s : 0.f;
}

// ---- chunked exclusive scan, no LDS ----
__global__ void k_chunksum(const int* cnt, int* csum, int n, int nchunks){
    int ch = blockIdx.x*256 + threadIdx.x;
    if (ch >= nchunks) return;
    int beg = ch*128, end = beg + 128;
    if (end > n) end = n;
    int s = 0;
    for (int i = beg; i < end; ++i) s += cnt[i];
    csum[ch] = s;
}
__global__ void k_chunkscan(const int* csum, int* cbase, int nchunks){
    if (blockIdx.x == 0 && threadIdx.x == 0){
        int run = 0;
        for (int ch = 0; ch < nchunks; ++ch){
            cbase[ch] = run;
            run += csum[ch];
        }
    }
}
__global__ void k_chunkfill(const int* cnt, const int* cbase, int* indptr,
                            int* cursor, int n, int nchunks){
    int ch = blockIdx.x*256 + threadIdx.x;
    if (ch >= nchunks) return;
    int beg = ch*128, end = beg + 128;
    if (end > n) end = n;
    int run = cbase[ch];
    for (int i = beg; i < end; ++i){
        indptr[i] = run;
        cursor[i] = run;
        run += cnt[i];
    }
}

// XCD-range-partitioned CSR fill. blockIdx%8 selects a key range; under the
// round-robin block->XCD dispatch, all writers of a given CSR destination line
// live on one XCD, so its L2 merges the scattered u16 stores before writeback.
__global__ void k_fill8(const int* nidx, const int* eidx,
                        int* cursor_n, unsigned short* nlist,
                        int* cursor_e, unsigned short* elist){
    int seg   = blockIdx.x & 7;
    int chunk = blockIdx.x >> 3;
    int i = chunk*256 + threadIdx.x;
    if (i >= N_INC) return;
    int n = nidx[i];
    int e = eidx[i];
    if (n / 6250 == seg){                 // 50000/8 = 6250
        int pn = atomicAdd(&cursor_n[n], 1);
        nlist[pn] = (unsigned short)e;
    }
    if (e / 1250 == seg){                 // 10000/8 = 1250
        int pe = atomicAdd(&cursor_e[e], 1);
        elist[pe] = (unsigned short)n;
    }
}

// gate GEMM v3: 4 nodes x 8 cols per thread (block = 64 nodes x 128 cols).
__global__ void k_gemm_gate(const void* x, const void* st, const void* W,
                            unsigned short* X1b, const int* flag){
    int bf = *flag;
    int tid = threadIdx.x;
    int c0 = (tid & 15) * 8;
    int n0 = blockIdx.x*64 + (tid >> 4)*4;
    int g0 = n0 < N_NODES, g1 = n0+1 < N_NODES, g2 = n0+2 < N_NODES, g3 = n0+3 < N_NODES;
    ACC8(A); ACC8(B); ACC8(C); ACC8(D);
    int i0 = n0*64;
    if (bf){
        const unsigned short* Wh = (const unsigned short*)W;
        const unsigned short* xh = (const unsigned short*)x;
        const unsigned short* sh = (const unsigned short*)st;
        for (int k = 0; k < 64; ++k){
            const unsigned short* w0 = Wh + k*128 + c0;
            const unsigned short* w1 = w0 + 64*128;
            float u0=bf2f(w0[0]),u1=bf2f(w0[1]),u2=bf2f(w0[2]),u3=bf2f(w0[3]),
                  u4=bf2f(w0[4]),u5=bf2f(w0[5]),u6=bf2f(w0[6]),u7=bf2f(w0[7]);
            float v0=bf2f(w1[0]),v1=bf2f(w1[1]),v2=bf2f(w1[2]),v3=bf2f(w1[3]),
                  v4=bf2f(w1[4]),v5=bf2f(w1[5]),v6=bf2f(w1[6]),v7=bf2f(w1[7]);
            float a, b;
            a = g0?bf2f(xh[i0+k]):0.f;     b = g0?bf2f(sh[i0+k]):0.f;     FMA8(A,a,b);
            a = g1?bf2f(xh[i0+64+k]):0.f;  b = g1?bf2f(sh[i0+64+k]):0.f;  FMA8(B,a,b);
            a = g2?bf2f(xh[i0+128+k]):0.f; b = g2?bf2f(sh[i0+128+k]):0.f; FMA8(C,a,b);
            a = g3?bf2f(xh[i0+192+k]):0.f; b = g3?bf2f(sh[i0+192+k]):0.f; FMA8(D,a,b);
        }
    } else {
        const float* Wf = (const float*)W;
        const float* xf = (const float*)x;
        const float* sf = (const float*)st;
        for (int k = 0; k < 64; ++k){
            const float* w0 = Wf + k*128 + c0;
            const float* w1 = w0 + 64*128;
            float u0=w0[0],u1=w0[1],u2=w0[2],u3=w0[3],u4=w0[4],u5=w0[5],u6=w0[6],u7=w0[7];
            float v0=w1[0],v1=w1[1],v2=w1[2],v3=w1[3],v4=w1[4],v5=w1[5],v6=w1[6],v7=w1[7];
            float a, b;
            a = g0?xf[i0+k]:0.f;     b = g0?sf[i0+k]:0.f;     FMA8(A,a,b);
            a = g1?xf[i0+64+k]:0.f;  b = g1?sf[i0+64+k]:0.f;  FMA8(B,a,b);
            a = g2?xf[i0+128+k]:0.f; b = g2?sf[i0+128+k]:0.f; FMA8(C,a,b);
            a = g3?xf[i0+192+k]:0.f; b = g3?sf[i0+192+k]:0.f; FMA8(D,a,b);
        }
    }
    if (g0){ unsigned short* o = X1b + n0*128 + c0;       STORE8(A,o); }
    if (g1){ unsigned short* o = X1b + (n0+1)*128 + c0;   STORE8(B,o); }
    if (g2){ unsigned short* o = X1b + (n0+2)*128 + c0;   STORE8(C,o); }
    if (g3){ unsigned short* o = X1b + (n0+3)*128 + c0;   STORE8(D,o); }
}

// cand GEMM v3: same tiling; cols 0-63 from Wc, 64-127 from Wr; second operand rs (f32).
__global__ void k_gemm_cand(const void* x, const float* rs, const void* Wc,
                            const void* Wr, unsigned short* X1b, const int* flag){
    int bf = *flag;
    int tid = threadIdx.x;
    int cq = tid & 15;
    int c0 = cq * 8;
    int cc = c0 & 63;
    int n0 = blockIdx.x*64 + (tid >> 4)*4;
    int g0 = n0 < N_NODES, g1 = n0+1 < N_NODES, g2 = n0+2 < N_NODES, g3 = n0+3 < N_NODES;
    const void* Wsel = (cq < 8) ? Wc : Wr;
    ACC8(A); ACC8(B); ACC8(C); ACC8(D);
    int i0 = n0*64;
    if (bf){
        const unsigned short* Wh = (const unsigned short*)Wsel;
        const unsigned short* xh = (const unsigned short*)x;
        for (int k = 0; k < 64; ++k){
            const unsigned short* w0 = Wh + k*64 + cc;
            const unsigned short* w1 = w0 + 64*64;
            float u0=bf2f(w0[0]),u1=bf2f(w0[1]),u2=bf2f(w0[2]),u3=bf2f(w0[3]),
                  u4=bf2f(w0[4]),u5=bf2f(w0[5]),u6=bf2f(w0[6]),u7=bf2f(w0[7]);
            float v0=bf2f(w1[0]),v1=bf2f(w1[1]),v2=bf2f(w1[2]),v3=bf2f(w1[3]),
                  v4=bf2f(w1[4]),v5=bf2f(w1[5]),v6=bf2f(w1[6]),v7=bf2f(w1[7]);
            float a, b;
            a = g0?bf2f(xh[i0+k]):0.f;     b = g0?rs[i0+k]:0.f;     FMA8(A,a,b);
            a = g1?bf2f(xh[i0+64+k]):0.f;  b = g1?rs[i0+64+k]:0.f;  FMA8(B,a,b);
            a = g2?bf2f(xh[i0+128+k]):0.f; b = g2?rs[i0+128+k]:0.f; FMA8(C,a,b);
            a = g3?bf2f(xh[i0+192+k]):0.f; b = g3?rs[i0+192+k]:0.f; FMA8(D,a,b);
        }
    } else {
        const float* Wf = (const float*)Wsel;
        const float* xf = (const float*)x;
        for (int k = 0; k < 64; ++k){
            const float* w0 = Wf + k*64 + cc;
            const float* w1 = w0 + 64*64;
            float u0=w0[0],u1=w0[1],u2=w0[2],u3=w0[3],u4=w0[4],u5=w0[5],u6=w0[6],u7=w0[7];
            float v0=w1[0],v1=w1[1],v2=w1[2],v3=w1[3],v4=w1[4],v5=w1[5],v6=w1[6],v7=w1[7];
            float a, b;
            a = g0?xf[i0+k]:0.f;     b = g0?rs[i0+k]:0.f;     FMA8(A,a,b);
            a = g1?xf[i0+64+k]:0.f;  b = g1?rs[i0+64+k]:0.f;  FMA8(B,a,b);
            a = g2?xf[i0+128+k]:0.f; b = g2?rs[i0+128+k]:0.f; FMA8(C,a,b);
            a = g3?xf[i0+192+k]:0.f; b = g3?rs[i0+192+k]:0.f; FMA8(D,a,b);
        }
    }
    if (g0){ unsigned short* o = X1b + n0*128 + c0;       STORE8(A,o); }
    if (g1){ unsigned short* o = X1b + (n0+1)*128 + c0;   STORE8(B,o); }
    if (g2){ unsigned short* o = X1b + (n0+2)*128 + c0;   STORE8(C,o); }
    if (g3){ unsigned short* o = X1b + (n0+3)*128 + c0;   STORE8(D,o); }
}

// gate edge gather (64 threads/edge, all 128 cols in one traversal).
// R19: unroll-by-8 with index prefetch -> 8 independent row loads in flight.
__global__ void k_gather_e_gate(const int* indptr_e, const int* Bc,
                                const unsigned short* elist,
                                const unsigned short* X1b, const void* hw,
                                const float* Binv, unsigned* mb, const int* flag){
    int bf = *flag;
    int t = blockIdx.x*256 + threadIdx.x;
    if (t >= N_EDGES*64) return;
    int e = t >> 6, p = t & 63;          // pair index 0..63 (128 bf16 cols)
    int beg = indptr_e[e], cnt = Bc[e];
    float acc0 = 0.f, acc1 = 0.f;
    int j = 0;
    for (; j + 8 <= cnt; j += 8){
        int n0 = elist[beg+j+0], n1 = elist[beg+j+1],
            n2 = elist[beg+j+2], n3 = elist[beg+j+3],
            n4 = elist[beg+j+4], n5 = elist[beg+j+5],
            n6 = elist[beg+j+6], n7 = elist[beg+j+7];
        unsigned w0 = *(const unsigned*)(X1b + n0*128 + p*2);
        unsigned w1 = *(const unsigned*)(X1b + n1*128 + p*2);
        unsigned w2 = *(const unsigned*)(X1b + n2*128 + p*2);
        unsigned w3 = *(const unsigned*)(X1b + n3*128 + p*2);
        unsigned w4 = *(const unsigned*)(X1b + n4*128 + p*2);
        unsigned w5 = *(const unsigned*)(X1b + n5*128 + p*2);
        unsigned w6 = *(const unsigned*)(X1b + n6*128 + p*2);
        unsigned w7 = *(const unsigned*)(X1b + n7*128 + p*2);
        acc0 += bf2f((unsigned short)(w0 & 0xFFFFu)); acc1 += bf2f((unsigned short)(w0 >> 16));
        acc0 += bf2f((unsigned short)(w1 & 0xFFFFu)); acc1 += bf2f((unsigned short)(w1 >> 16));
        acc0 += bf2f((unsigned short)(w2 & 0xFFFFu)); acc1 += bf2f((unsigned short)(w2 >> 16));
        acc0 += bf2f((unsigned short)(w3 & 0xFFFFu)); acc1 += bf2f((unsigned short)(w3 >> 16));
        acc0 += bf2f((unsigned short)(w4 & 0xFFFFu)); acc1 += bf2f((unsigned short)(w4 >> 16));
        acc0 += bf2f((unsigned short)(w5 & 0xFFFFu)); acc1 += bf2f((unsigned short)(w5 >> 16));
        acc0 += bf2f((unsigned short)(w6 & 0xFFFFu)); acc1 += bf2f((unsigned short)(w6 >> 16));
        acc0 += bf2f((unsigned short)(w7 & 0xFFFFu)); acc1 += bf2f((unsigned short)(w7 >> 16));
    }
    for (; j < cnt; ++j){
        int n = elist[beg + j];
        unsigned v = *(const unsigned*)(X1b + n*128 + p*2);
        acc0 += bf2f((unsigned short)(v & 0xFFFFu));
        acc1 += bf2f((unsigned short)(v >> 16));
    }
    float wsc = ldv(hw, e, bf) * Binv[e];
    unsigned lo = f2bf(acc0 * wsc);
    unsigned hi = f2bf(acc1 * wsc);
    mb[e*64 + p] = lo | (hi << 16);
}

// cand edge gather: 32 threads/edge, cols 0-63 of X1 (CP=32). elist u16. Unroll-by-8.
__global__ void k_gather_e2(const int* indptr_e, const int* Bc,
                            const unsigned short* elist,
                            const unsigned short* X1b, const void* hw,
                            const float* Binv, unsigned* mb, int pairBase, int CP,
                            const int* flag){
    int bf = *flag;
    int t = blockIdx.x*256 + threadIdx.x;
    if (t >= N_EDGES*32) return;
    int e = t >> 5, p = t & 31;
    int cp = pairBase + p;
    int beg = indptr_e[e], cnt = Bc[e];
    float acc0 = 0.f, acc1 = 0.f;
    int j = 0;
    for (; j + 8 <= cnt; j += 8){
        int n0 = elist[beg+j+0], n1 = elist[beg+j+1],
            n2 = elist[beg+j+2], n3 = elist[beg+j+3],
            n4 = elist[beg+j+4], n5 = elist[beg+j+5],
            n6 = elist[beg+j+6], n7 = elist[beg+j+7];
        unsigned w0 = *(const unsigned*)(X1b + n0*128 + cp*2);
        unsigned w1 = *(const unsigned*)(X1b + n1*128 + cp*2);
        unsigned w2 = *(const unsigned*)(X1b + n2*128 + cp*2);
        unsigned w3 = *(const unsigned*)(X1b + n3*128 + cp*2);
        unsigned w4 = *(const unsigned*)(X1b + n4*128 + cp*2);
        unsigned w5 = *(const unsigned*)(X1b + n5*128 + cp*2);
        unsigned w6 = *(const unsigned*)(X1b + n6*128 + cp*2);
        unsigned w7 = *(const unsigned*)(X1b + n7*128 + cp*2);
        acc0 += bf2f((unsigned short)(w0 & 0xFFFFu)); acc1 += bf2f((unsigned short)(w0 >> 16));
        acc0 += bf2f((unsigned short)(w1 & 0xFFFFu)); acc1 += bf2f((unsigned short)(w1 >> 16));
        acc0 += bf2f((unsigned short)(w2 & 0xFFFFu)); acc1 += bf2f((unsigned short)(w2 >> 16));
        acc0 += bf2f((unsigned short)(w3 & 0xFFFFu)); acc1 += bf2f((unsigned short)(w3 >> 16));
        acc0 += bf2f((unsigned short)(w4 & 0xFFFFu)); acc1 += bf2f((unsigned short)(w4 >> 16));
        acc0 += bf2f((unsigned short)(w5 & 0xFFFFu)); acc1 += bf2f((unsigned short)(w5 >> 16));
        acc0 += bf2f((unsigned short)(w6 & 0xFFFFu)); acc1 += bf2f((unsigned short)(w6 >> 16));
        acc0 += bf2f((unsigned short)(w7 & 0xFFFFu)); acc1 += bf2f((unsigned short)(w7 >> 16));
    }
    for (; j < cnt; ++j){
        int n = elist[beg + j];
        unsigned v = *(const unsigned*)(X1b + n*128 + cp*2);
        acc0 += bf2f((unsigned short)(v & 0xFFFFu));
        acc1 += bf2f((unsigned short)(v >> 16));
    }
    float wsc = ldv(hw, e, bf) * Binv[e];
    unsigned lo = f2bf(acc0 * wsc);
    unsigned hi = f2bf(acc1 * wsc);
    mb[e*CP + cp] = lo | (hi << 16);     // CP = C/2 pairs per edge
}

// fused node gather + gate prep: thread per (node, 4-col group). Unroll-by-4
// (2 loads/iter -> 8 in flight).
__global__ void k_gather_prep_gate(const int* indptr_n, const int* Dc,
                                   const unsigned short* nlist, const unsigned* mb,
                                   const void* x, const void* st,
                                   const float* Dinv, const void* gb,
                                   float* P, const int* flag){
    int bf = *flag;
    int t = blockIdx.x*256 + threadIdx.x;
    if (t >= N_NODES*32) return;
    int n = t >> 5, g = t & 31;
    int c = g*4;
    int beg = indptr_n[n], cnt = Dc[n];
    float a0 = 0.f, a1 = 0.f, a2 = 0.f, a3 = 0.f;
    int j = 0;
    for (; j + 4 <= cnt; j += 4){
        int e0 = nlist[beg+j+0], e1 = nlist[beg+j+1],
            e2 = nlist[beg+j+2], e3 = nlist[beg+j+3];
        const unsigned* q0 = mb + e0*64 + g*2;
        const unsigned* q1 = mb + e1*64 + g*2;
        const unsigned* q2 = mb + e2*64 + g*2;
        const unsigned* q3 = mb + e3*64 + g*2;
        unsigned va0 = q0[0], vb0 = q0[1];
        unsigned va1 = q1[0], vb1 = q1[1];
        unsigned va2 = q2[0], vb2 = q2[1];
        unsigned va3 = q3[0], vb3 = q3[1];
        a0 += bf2f((unsigned short)(va0 & 0xFFFFu)); a1 += bf2f((unsigned short)(va0 >> 16));
        a2 += bf2f((unsigned short)(vb0 & 0xFFFFu)); a3 += bf2f((unsigned short)(vb0 >> 16));
        a0 += bf2f((unsigned short)(va1 & 0xFFFFu)); a1 += bf2f((unsigned short)(va1 >> 16));
        a2 += bf2f((unsigned short)(vb1 & 0xFFFFu)); a3 += bf2f((unsigned short)(vb1 >> 16));
        a0 += bf2f((unsigned short)(va2 & 0xFFFFu)); a1 += bf2f((unsigned short)(va2 >> 16));
        a2 += bf2f((unsigned short)(vb2 & 0xFFFFu)); a3 += bf2f((unsigned short)(vb2 >> 16));
        a0 += bf2f((unsigned short)(va3 & 0xFFFFu)); a1 += bf2f((unsigned short)(va3 >> 16));
        a2 += bf2f((unsigned short)(vb3 & 0xFFFFu)); a3 += bf2f((unsigned short)(vb3 >> 16));
    }
    for (; j < cnt; ++j){
        int e = nlist[beg + j];
        const unsigned* q = mb + e*64 + g*2;
        unsigned va = q[0], vb = q[1];
        a0 += bf2f((unsigned short)(va & 0xFFFFu));
        a1 += bf2f((unsigned short)(va >> 16));
        a2 += bf2f((unsigned short)(vb & 0xFFFFu));
        a3 += bf2f((unsigned short)(vb >> 16));
    }
    float di = Dinv[n];
    float b0, b1, b2, b3;
    if (c < 64){
        b0 = ldv(x, n*64 + c, bf);     b1 = ldv(x, n*64 + c + 1, bf);
        b2 = ldv(x, n*64 + c + 2, bf); b3 = ldv(x, n*64 + c + 3, bf);
    } else {
        int cc = c - 64;
        b0 = ldv(st, n*64 + cc, bf);     b1 = ldv(st, n*64 + cc + 1, bf);
        b2 = ldv(st, n*64 + cc + 2, bf); b3 = ldv(st, n*64 + cc + 3, bf);
    }
    float v0 = b0 + di*a0 + ldv(gb, c, bf);
    float v1 = b1 + di*a1 + ldv(gb, c + 1, bf);
    float v2 = b2 + di*a2 + ldv(gb, c + 2, bf);
    float v3 = b3 + di*a3 + ldv(gb, c + 3, bf);
    if (v0 < 0.f) v0 = 0.f;
    if (v1 < 0.f) v1 = 0.f;
    if (v2 < 0.f) v2 = 0.f;
    if (v3 < 0.f) v3 = 0.f;
    float* o = P + n*128 + c;
    o[0] = v0; o[1] = v1; o[2] = v2; o[3] = v3;
}

// fused node gather + cand prep: thread per (node, 4-col group), m bf16 (CP=32). Unroll-by-4.
__global__ void k_gather_prep_cand(const int* indptr_n, const int* Dc,
                                   const unsigned short* nlist, const unsigned* mb,
                                   const unsigned short* X1b, const float* Dinv,
                                   const void* cbv, const void* crb,
                                   float* P2, const int* flag){
    int bf = *flag;
    int t = blockIdx.x*256 + threadIdx.x;
    if (t >= N_NODES*16) return;
    int n = t >> 4, g = t & 15;
    int c = g*4;
    int beg = indptr_n[n], cnt = Dc[n];
    float a0 = 0.f, a1 = 0.f, a2 = 0.f, a3 = 0.f;
    int j = 0;
    for (; j + 4 <= cnt; j += 4){
        int e0 = nlist[beg+j+0], e1 = nlist[beg+j+1],
            e2 = nlist[beg+j+2], e3 = nlist[beg+j+3];
        const unsigned* q0 = mb + e0*32 + g*2;
        const unsigned* q1 = mb + e1*32 + g*2;
        const unsigned* q2 = mb + e2*32 + g*2;
        const unsigned* q3 = mb + e3*32 + g*2;
        unsigned va0 = q0[0], vb0 = q0[1];
        unsigned va1 = q1[0], vb1 = q1[1];
        unsigned va2 = q2[0], vb2 = q2[1];
        unsigned va3 = q3[0], vb3 = q3[1];
        a0 += bf2f((unsigned short)(va0 & 0xFFFFu)); a1 += bf2f((unsigned short)(va0 >> 16));
        a2 += bf2f((unsigned short)(vb0 & 0xFFFFu)); a3 += bf2f((unsigned short)(vb0 >> 16));
        a0 += bf2f((unsigned short)(va1 & 0xFFFFu)); a1 += bf2f((unsigned short)(va1 >> 16));
        a2 += bf2f((unsigned short)(vb1 & 0xFFFFu)); a3 += bf2f((unsigned short)(vb1 >> 16));
        a0 += bf2f((unsigned short)(va2 & 0xFFFFu)); a1 += bf2f((unsigned short)(va2 >> 16));
        a2 += bf2f((unsigned short)(vb2 & 0xFFFFu)); a3 += bf2f((unsigned short)(vb2 >> 16));
        a0 += bf2f((unsigned short)(va3 & 0xFFFFu)); a1 += bf2f((unsigned short)(va3 >> 16));
        a2 += bf2f((unsigned short)(vb3 & 0xFFFFu)); a3 += bf2f((unsigned short)(vb3 >> 16));
    }
    for (; j < cnt; ++j){
        int e = nlist[beg + j];
        const unsigned* q = mb + e*32 + g*2;
        unsigned va = q[0], vb = q[1];
        a0 += bf2f((unsigned short)(va & 0xFFFFu));
        a1 += bf2f((unsigned short)(va >> 16));
        a2 += bf2f((unsigned short)(vb & 0xFFFFu));
        a3 += bf2f((unsigned short)(vb >> 16));
    }
    float di = Dinv[n];
    float v0 = bf2f(X1b[n*128 + 64 + c])     + ldv(crb, c, bf)     + di*a0 + ldv(cbv, c, bf);
    float v1 = bf2f(X1b[n*128 + 64 + c + 1]) + ldv(crb, c + 1, bf) + di*a1 + ldv(cbv, c + 1, bf);
    float v2 = bf2f(X1b[n*128 + 64 + c + 2]) + ldv(crb, c + 2, bf) + di*a2 + ldv(cbv, c + 2, bf);
    float v3 = bf2f(X1b[n*128 + 64 + c + 3]) + ldv(crb, c + 3, bf) + di*a3 + ldv(cbv, c + 3, bf);
    if (v0 < 0.f) v0 = 0.f;
    if (v1 < 0.f) v1 = 0.f;
    if (v2 < 0.f) v2 = 0.f;
    if (v3 < 0.f) v3 = 0.f;
    float* o = P2 + n*64 + c;
    o[0] = v0; o[1] = v1; o[2] = v2; o[3] = v3;
}

// row stats: thread per node, 64-thread blocks (block footprint fits L1).
__global__ void k_stat(const float* P, float* pstat, int nrows, int C){
    int n = blockIdx.x*64 + threadIdx.x;
    if (n >= nrows) return;
    float s = 0.f, sq = 0.f;
    for (int c = 0; c < C; ++c){
        float v = P[n*C + c];
        s += v; sq += v*v;
    }
    pstat[n*2]     = s;
    pstat[n*2 + 1] = sq;
}

// gate fin: thread per (node, col<64).
__global__ void k_gate_fin2(const void* st, const float* P, const float* pstat,
                            const void* lng, const void* lnb,
                            float* zbuf, float* rs, const int* flag){
    int bf = *flag;
    int t = blockIdx.x*256 + threadIdx.x;
    if (t >= N_NODES*64) return;
    int n = t >> 6, c = t & 63;
    float s  = pstat[2*n];
    float sq = pstat[2*n + 1];
    float mu = s * (1.f/128.f);
    float var = sq * (1.f/128.f) - mu*mu;
    if (var < 0.f) var = 0.f;
    float inv = 1.f / sqrtf(var + 1e-5f);
    float v0 = P[n*128 + c];
    float v1 = P[n*128 + 64 + c];
    float u0 = (v0 - mu)*inv*ldv(lng, c, bf)      + ldv(lnb, c, bf);
    float u1 = (v1 - mu)*inv*ldv(lng, 64 + c, bf) + ldv(lnb, 64 + c, bf);
    float z = 1.f/(1.f + expf(-u0));
    float r = 1.f/(1.f + expf(-u1));
    float s1 = ldv(st, t, bf);
    zbuf[t] = z;
    rs[t]   = r * s1;
}

// cand fin: thread per (node, col). LN + tanh + GRU blend -> out.
__global__ void k_cand_fin2(const void* st, const float* P2, const float* pstat,
                            const void* lng, const void* lnb, const float* zbuf,
                            void* out, const int* flag){
    int bf = *flag;
    int t = blockIdx.x*256 + threadIdx.x;
    if (t >= N_NODES*64) return;
    int n = t >> 6, c = t & 63;
    float s  = pstat[2*n];
    float sq = pstat[2*n + 1];
    float mu = s * (1.f/64.f);
    float var = sq * (1.f/64.f) - mu*mu;
    if (var < 0.f) var = 0.f;
    float inv = 1.f / sqrtf(var + 1e-5f);
    float v = P2[t];
    float u = (v - mu)*inv*ldv(lng, c, bf) + ldv(lnb, c, bf);
    float hc = tanhf(u);
    float z = zbuf[t];
    float sv = ldv(st, t, bf);
    float res = (1.f - z)*sv + z*hc;
    if (bf) ((unsigned short*)out)[t] = f2bf(res);
    else    ((float*)out)[t] = res;
}

extern "C" void kernel_launch(void* const* d_in, const int* in_sizes, int n_in,
                              void* d_out, int out_size, void* d_ws, size_t ws_size,
                              hipStream_t stream){
    const void* x      = d_in[0];
    const void* state  = d_in[1];
    const int*  hidx   = (const int*)d_in[2];
    const void* hw     = d_in[3];
    const void* gate_W = d_in[4];
    const void* gate_b = d_in[5];
    const void* glng   = d_in[6];
    const void* glnb   = d_in[7];
    const void* cand_W = d_in[8];
    const void* cand_b = d_in[9];
    const void* clng   = d_in[10];
    const void* clnb   = d_in[11];
    const void* crW    = d_in[12];
    const void* crb    = d_in[13];
    (void)in_sizes; (void)n_in; (void)ws_size; (void)out_size;

    const int* nidx = hidx;
    const int* eidx = hidx + N_INC;

    const int NCH_N = (N_NODES + 127)/128;   // 391
    const int NCH_E = (N_EDGES + 127)/128;   // 79

    // ---- workspace (byte offsets, 256B-aligned, total ~73.5 MB) ----
    char* w = (char*)d_ws;
    int*   flag     = (int*)  (w);
    float* Dinv     = (float*)(w + 256);        // 50048 f (computed by k_dinv)
    int*   Bc       = (int*)  (w + 200448);     // 10048 i  (Bc,Dc contiguous: zeroed)
    int*   Dc       = (int*)  (w + 240640);     // 50048 i
    float* Binv     = (float*)(w + 440832);     // 10048 f
    int*   indptr_n = (int*)  (w + 481024);     // 50048 i
    int*   cursor_n = (int*)  (w + 681216);     // 50048 i
    int*   indptr_e = (int*)  (w + 881408);     // 10048 i
    int*   cursor_e = (int*)  (w + 921600);     // 10048 i
    int*   csum_n   = (int*)  (w + 961792);     // 512 i
    int*   cbase_n  = (int*)  (w + 963840);     // 512 i
    int*   csum_e   = (int*)  (w + 965888);     // 256 i
    int*   cbase_e  = (int*)  (w + 966912);     // 256 i
    unsigned short* nlist = (unsigned short*)(w + 967936);  // 800000 u16
    unsigned short* elist = (unsigned short*)(w + 2567936); // 800000 u16 (node ids < 65536)
    unsigned* mb    = (unsigned*)(w + 5767936); // 10000*64 u32 (=128 bf16 cols)
    unsigned short* X1b = (unsigned short*)(w + 8327936);   // 50000*128 u16
    float* P        = (float*)(w + 21127936);   // 50000*128 f (gate P; cand P2 aliases)
    float* P2       = P;
    float* zbuf     = (float*)(w + 46727936);   // 50000*64 f
    float* rs       = (float*)(w + 59527936);   // 50000*64 f
    float* pstat_g  = (float*)(w + 72327936);   // 100000 f
    float* pstat_c  = (float*)(w + 73127936);   // 100000 f -> ends 73527936

    // dtype detect
    k_detect<<<1, 64, 0, stream>>>((const unsigned short*)hw, flag);

    // zero Bc,Dc (contiguous 60096 words)
    k_zero<<<(60096 + 255)/256, 256, 0, stream>>>((float*)(w + 200448), 60096);

    // degrees + CSR build
    k_count<<<(N_INC + 255)/256, 256, 0, stream>>>(nidx, eidx, Dc, Bc);
    k_binv<<<(N_EDGES + 255)/256, 256, 0, stream>>>(Bc, Binv);
    k_chunksum<<<(NCH_N + 255)/256, 256, 0, stream>>>(Dc, csum_n, N_NODES, NCH_N);
    k_chunkscan<<<1, 64, 0, stream>>>(csum_n, cbase_n, NCH_N);
    k_chunkfill<<<(NCH_N + 255)/256, 256, 0, stream>>>(Dc, cbase_n, indptr_n, cursor_n,
                                                       N_NODES, NCH_N);
    k_chunksum<<<(NCH_E + 255)/256, 256, 0, stream>>>(Bc, csum_e, N_EDGES, NCH_E);
    k_chunkscan<<<1, 64, 0, stream>>>(csum_e, cbase_e, NCH_E);
    k_chunkfill<<<(NCH_E + 255)/256, 256, 0, stream>>>(Bc, cbase_e, indptr_e, cursor_e,
                                                       N_EDGES, NCH_E);
    k_fill8<<<8*((N_INC + 255)/256), 256, 0, stream>>>(nidx, eidx, cursor_n, nlist,
                                                       cursor_e, elist);
    k_dinv<<<(N_NODES + 255)/256, 256, 0, stream>>>(indptr_n, Dc, nlist, hw, Dinv, flag);

    // ---- gate path ----
    k_gemm_gate<<<(N_NODES + 63)/64, 256, 0, stream>>>(x, state, gate_W, X1b, flag);
    k_gather_e_gate<<<(N_EDGES*64 + 255)/256, 256, 0, stream>>>(indptr_e, Bc, elist,
                                                                X1b, hw, Binv, mb, flag);
    k_gather_prep_gate<<<(N_NODES*32 + 255)/256, 256, 0, stream>>>(indptr_n, Dc, nlist,
                                                                   mb, x, state, Dinv,
                                                                   gate_b, P, flag);
    k_stat<<<(N_NODES + 63)/64, 64, 0, stream>>>(P, pstat_g, N_NODES, 128);
    k_gate_fin2<<<(N_NODES*64 + 255)/256, 256, 0, stream>>>(state, P, pstat_g,
                                                            glng, glnb, zbuf, rs, flag);

    // ---- candidate path ----
    k_gemm_cand<<<(N_NODES + 63)/64, 256, 0, stream>>>(x, rs, cand_W, crW, X1b, flag);
    k_gather_e2<<<(N_EDGES*32 + 255)/256, 256, 0, stream>>>(indptr_e, Bc, elist, X1b,
                                                            hw, Binv, mb, 0, 32, flag);
    k_gather_prep_cand<<<(N_NODES*16 + 255)/256, 256, 0, stream>>>(indptr_n, Dc, nlist,
                                                                   mb, X1b, Dinv, cand_b,
                                                                   crb, P2, flag);
    k_stat<<<(N_NODES + 63)/64, 64, 0, stream>>>(P2, pstat_c, N_NODES, 64);
    k_cand_fin2<<<(N_NODES*64 + 255)/256, 256, 0, stream>>>(state, P2, pstat_c,
                                                            clng, clnb, zbuf,
                                                            d_out, flag);
}